// Round 2
// baseline (263.217 us; speedup 1.0000x reference)
//
#include <hip/hip_runtime.h>
#include <math.h>

#define CCH 256
#define CROP 7
#define NCELL 49

// Native vector type: required by __builtin_nontemporal_store (HIP float4 is a
// class and is rejected). Same 16B loads/stores either way.
typedef float f32x4 __attribute__((ext_vector_type(4)));

// Per-cell address/weight setup, variables suffixed with S so two cells can be
// in flight simultaneously (8 independent global loads per wave iteration).
#define CELL_ADDR(S, cell)                                                        \
    const int   iy##S  = (cell) / CROP;                                           \
    const int   ix##S  = (cell) % CROP;                                           \
    const float ys##S  = ry1 * Hf + (float)iy##S * ystep;                         \
    const float xs##S  = cx1 * Hf + (float)ix##S * xstep;                         \
    const float y0f##S = floorf(ys##S);                                           \
    const float x0f##S = floorf(xs##S);                                           \
    const float ly##S  = ys##S - y0f##S;                                          \
    const float lx##S  = xs##S - x0f##S;                                          \
    const int   y0##S  = (int)fminf(fmaxf(y0f##S,        0.0f), Hf);              \
    const int   y1i##S = (int)fminf(fmaxf(y0f##S + 1.0f, 0.0f), Hf);              \
    const int   x0##S  = (int)fminf(fmaxf(x0f##S,        0.0f), Hf);              \
    const int   x1i##S = (int)fminf(fmaxf(x0f##S + 1.0f, 0.0f), Hf);              \
    const bool  ok##S  = (ys##S >= 0.0f) && (ys##S <= Hf) &&                      \
                         (xs##S >= 0.0f) && (xs##S <= Hf);                        \
    const f32x4* p00##S = (const f32x4*)(f + img + ((size_t)y0##S  * s + x0##S ) * CCH) + c4; \
    const f32x4* p01##S = (const f32x4*)(f + img + ((size_t)y0##S  * s + x1i##S) * CCH) + c4; \
    const f32x4* p10##S = (const f32x4*)(f + img + ((size_t)y1i##S * s + x0##S ) * CCH) + c4; \
    const f32x4* p11##S = (const f32x4*)(f + img + ((size_t)y1i##S * s + x1i##S) * CCH) + c4;

// Bilinear lerp (identical op order to reference) + nontemporal streamed store.
#define LERP_STORE(S, v00, v01, v10, v11, cell)                                   \
    {                                                                             \
        f32x4 val;                                                                \
        float tx = v00.x + lx##S * (v01.x - v00.x);                               \
        float bx = v10.x + lx##S * (v11.x - v10.x);                               \
        val.x = tx + ly##S * (bx - tx);                                           \
        float ty = v00.y + lx##S * (v01.y - v00.y);                               \
        float by = v10.y + lx##S * (v11.y - v10.y);                               \
        val.y = ty + ly##S * (by - ty);                                           \
        float tz = v00.z + lx##S * (v01.z - v00.z);                               \
        float bz = v10.z + lx##S * (v11.z - v10.z);                               \
        val.z = tz + ly##S * (bz - tz);                                           \
        float tw = v00.w + lx##S * (v01.w - v00.w);                               \
        float bw = v10.w + lx##S * (v11.w - v10.w);                               \
        val.w = tw + ly##S * (bw - tw);                                           \
        if (!ok##S) { val.x = 0.0f; val.y = 0.0f; val.z = 0.0f; val.w = 0.0f; }   \
        __builtin_nontemporal_store(val, outbn + (size_t)(cell) * (CCH / 4));     \
    }

__global__ __launch_bounds__(256, 4) void roi_align_kernel(
    const f32x4* __restrict__ boxes,    // (B*N) boxes; cols [row1, col1, row2, col2]
    const float* __restrict__ f0,
    const float* __restrict__ f1,
    const float* __restrict__ f2,
    const float* __restrict__ f3,
    const float* __restrict__ f4,
    const int*  __restrict__ image_shape,
    float* __restrict__ out,
    int N)                              // boxes per batch image
{
    const int bn   = blockIdx.x;        // one block per box
    const int wave = threadIdx.x >> 6;  // 0..3
    const int c4   = threadIdx.x & 63;  // channel group: floats c4*4..c4*4+3
    const int b    = bn / N;

    // ---- box setup: once per block (was once per cell = 49x redundant) ----
    const f32x4 box = boxes[bn];        // uniform index -> scalar load
    const float ry1 = box.x;   // row start  (col 0)
    const float cx1 = box.y;   // col start  (col 1)
    const float ry2 = box.z;   // row end    (col 2)
    const float cx2 = box.w;   // col end    (col 3)

    const float h = cx2 - cx1;
    const float w = ry2 - ry1;

    const float area  = (float)(image_shape[0] * image_shape[1]);
    const float canon = 56.0f / sqrtf(area);
    const float lvlf  = log2f(sqrtf(h * w) / canon);
    int lvl = (int)rintf(lvlf);         // half-to-even, matches jnp.round
    lvl = lvl < 0 ? 0 : (lvl > 4 ? 4 : lvl);

    const float* f; int s;
    if      (lvl == 0) { f = f0; s = 256; }
    else if (lvl == 1) { f = f1; s = 128; }
    else if (lvl == 2) { f = f2; s = 64;  }
    else if (lvl == 3) { f = f3; s = 32;  }
    else               { f = f4; s = 16;  }

    const float Hf = (float)(s - 1);    // square levels: Wf == Hf
    const float ystep = (ry2 - ry1) * Hf / 6.0f;
    const float xstep = (cx2 - cx1) * Hf / 6.0f;

    const size_t img = (size_t)b * s * s * CCH;
    f32x4* outbn = (f32x4*)(out + (size_t)bn * (NCELL * CCH)) + c4;

    // Each wave handles cell pairs {base, base+1}, base = wave*2 + 8k.
    // Union over 4 waves covers cells 0..48 exactly once.
    for (int base = wave * 2; base < NCELL; base += 8) {
        const int  cA   = base;
        const bool hasB = (base + 1) < NCELL;
        const int  cB   = hasB ? base + 1 : base;   // safe duplicate load if no B

        CELL_ADDR(A, cA)
        CELL_ADDR(B, cB)

        // Issue all 8 independent 16B loads before consuming any.
        const f32x4 a00 = *p00A; const f32x4 a01 = *p01A;
        const f32x4 a10 = *p10A; const f32x4 a11 = *p11A;
        const f32x4 b00 = *p00B; const f32x4 b01 = *p01B;
        const f32x4 b10 = *p10B; const f32x4 b11 = *p11B;

        LERP_STORE(A, a00, a01, a10, a11, cA)
        if (hasB) {
            LERP_STORE(B, b00, b01, b10, b11, cB)
        }
    }
}

extern "C" void kernel_launch(void* const* d_in, const int* in_sizes, int n_in,
                              void* d_out, int out_size, void* d_ws, size_t ws_size,
                              hipStream_t stream) {
    const f32x4*  boxes = (const f32x4*)d_in[0];
    const float*  f0    = (const float*)d_in[1];
    const float*  f1    = (const float*)d_in[2];
    const float*  f2    = (const float*)d_in[3];
    const float*  f3    = (const float*)d_in[4];
    const float*  f4    = (const float*)d_in[5];
    const int*    ishp  = (const int*)d_in[6];
    float*        out   = (float*)d_out;

    const int BN = in_sizes[0] / 4;                    // B*N
    const int B  = in_sizes[1] / (256 * 256 * 256);    // from feat0
    const int N  = BN / B;

    dim3 grid(BN);
    roi_align_kernel<<<grid, 256, 0, stream>>>(boxes, f0, f1, f2, f3, f4, ishp, out, N);
}

// Round 3
// 252.046 us; speedup vs baseline: 1.0443x; 1.0443x over previous
//
#include <hip/hip_runtime.h>
#include <math.h>

#define CCH 256
#define CROP 7
#define NCELL 49
#define NPAIR 25   // ceil(49/2) cell pairs per box

// Native vector type: __builtin_nontemporal_store rejects HIP's float4 class.
typedef float f32x4 __attribute__((ext_vector_type(4)));

// Per-cell address/weight setup, suffixed so two cells can be in flight
// simultaneously (8 independent 16B global loads per wave).
#define CELL_ADDR(S, cell)                                                        \
    const int   iy##S  = (cell) / CROP;                                           \
    const int   ix##S  = (cell) % CROP;                                           \
    const float ys##S  = ry1 * Hf + (float)iy##S * ystep;                         \
    const float xs##S  = cx1 * Hf + (float)ix##S * xstep;                         \
    const float y0f##S = floorf(ys##S);                                           \
    const float x0f##S = floorf(xs##S);                                           \
    const float ly##S  = ys##S - y0f##S;                                          \
    const float lx##S  = xs##S - x0f##S;                                          \
    const int   y0##S  = (int)fminf(fmaxf(y0f##S,        0.0f), Hf);              \
    const int   y1i##S = (int)fminf(fmaxf(y0f##S + 1.0f, 0.0f), Hf);              \
    const int   x0##S  = (int)fminf(fmaxf(x0f##S,        0.0f), Hf);              \
    const int   x1i##S = (int)fminf(fmaxf(x0f##S + 1.0f, 0.0f), Hf);              \
    const bool  ok##S  = (ys##S >= 0.0f) && (ys##S <= Hf) &&                      \
                         (xs##S >= 0.0f) && (xs##S <= Hf);                        \
    const f32x4* p00##S = (const f32x4*)(f + img + ((size_t)y0##S  * s + x0##S ) * CCH) + c4; \
    const f32x4* p01##S = (const f32x4*)(f + img + ((size_t)y0##S  * s + x1i##S) * CCH) + c4; \
    const f32x4* p10##S = (const f32x4*)(f + img + ((size_t)y1i##S * s + x0##S ) * CCH) + c4; \
    const f32x4* p11##S = (const f32x4*)(f + img + ((size_t)y1i##S * s + x1i##S) * CCH) + c4;

// Bilinear lerp (identical op order to reference) + nontemporal streamed store.
#define LERP_STORE(S, v00, v01, v10, v11, cell)                                   \
    {                                                                             \
        f32x4 val;                                                                \
        float tx = v00.x + lx##S * (v01.x - v00.x);                               \
        float bx = v10.x + lx##S * (v11.x - v10.x);                               \
        val.x = tx + ly##S * (bx - tx);                                           \
        float ty = v00.y + lx##S * (v01.y - v00.y);                               \
        float by = v10.y + lx##S * (v11.y - v10.y);                               \
        val.y = ty + ly##S * (by - ty);                                           \
        float tz = v00.z + lx##S * (v01.z - v00.z);                               \
        float bz = v10.z + lx##S * (v11.z - v10.z);                               \
        val.z = tz + ly##S * (bz - tz);                                           \
        float tw = v00.w + lx##S * (v01.w - v00.w);                               \
        float bw = v10.w + lx##S * (v11.w - v10.w);                               \
        val.w = tw + ly##S * (bw - tw);                                           \
        if (!ok##S) { val.x = 0.0f; val.y = 0.0f; val.z = 0.0f; val.w = 0.0f; }   \
        __builtin_nontemporal_store(val, outbn + (size_t)(cell) * (CCH / 4));     \
    }

__global__ __launch_bounds__(64) void roi_align_kernel(
    const f32x4* __restrict__ boxes,    // (B*N) boxes; cols [row1, col1, row2, col2]
    const float* __restrict__ f0,
    const float* __restrict__ f1,
    const float* __restrict__ f2,
    const float* __restrict__ f3,
    const float* __restrict__ f4,
    const int*  __restrict__ image_shape,
    float* __restrict__ out,
    int N)                              // boxes per batch image
{
    const int pair = blockIdx.x;        // 0..24 -> cells {2p, 2p+1}
    const int bn   = blockIdx.y;        // 0..B*N-1
    const int c4   = threadIdx.x;       // 0..63 -> channels c4*4..c4*4+3
    const int b    = bn / N;

    // ---- box setup (once per 2 cells) ----
    const f32x4 box = boxes[bn];        // uniform index -> scalar load
    const float ry1 = box.x;   // row start  (col 0)
    const float cx1 = box.y;   // col start  (col 1)
    const float ry2 = box.z;   // row end    (col 2)
    const float cx2 = box.w;   // col end    (col 3)

    const float h = cx2 - cx1;
    const float w = ry2 - ry1;

    const float area  = (float)(image_shape[0] * image_shape[1]);
    const float canon = 56.0f / sqrtf(area);
    const float lvlf  = log2f(sqrtf(h * w) / canon);
    int lvl = (int)rintf(lvlf);         // half-to-even, matches jnp.round
    lvl = lvl < 0 ? 0 : (lvl > 4 ? 4 : lvl);

    const float* f; int s;
    if      (lvl == 0) { f = f0; s = 256; }
    else if (lvl == 1) { f = f1; s = 128; }
    else if (lvl == 2) { f = f2; s = 64;  }
    else if (lvl == 3) { f = f3; s = 32;  }
    else               { f = f4; s = 16;  }

    const float Hf = (float)(s - 1);    // square levels: Wf == Hf
    const float ystep = (ry2 - ry1) * Hf / 6.0f;
    const float xstep = (cx2 - cx1) * Hf / 6.0f;

    const size_t img = (size_t)b * s * s * CCH;
    f32x4* outbn = (f32x4*)(out + (size_t)bn * (NCELL * CCH)) + c4;

    const int  cA   = pair * 2;
    const bool hasB = (cA + 1) < NCELL;  // pair 24 has only cell 48
    const int  cB   = hasB ? cA + 1 : cA;   // safe duplicate load if no B

    CELL_ADDR(A, cA)
    CELL_ADDR(B, cB)

    // Issue all 8 independent 16B loads before consuming any.
    const f32x4 a00 = *p00A; const f32x4 a01 = *p01A;
    const f32x4 a10 = *p10A; const f32x4 a11 = *p11A;
    const f32x4 b00 = *p00B; const f32x4 b01 = *p01B;
    const f32x4 b10 = *p10B; const f32x4 b11 = *p11B;

    LERP_STORE(A, a00, a01, a10, a11, cA)
    if (hasB) {
        LERP_STORE(B, b00, b01, b10, b11, cB)
    }
}

extern "C" void kernel_launch(void* const* d_in, const int* in_sizes, int n_in,
                              void* d_out, int out_size, void* d_ws, size_t ws_size,
                              hipStream_t stream) {
    const f32x4*  boxes = (const f32x4*)d_in[0];
    const float*  f0    = (const float*)d_in[1];
    const float*  f1    = (const float*)d_in[2];
    const float*  f2    = (const float*)d_in[3];
    const float*  f3    = (const float*)d_in[4];
    const float*  f4    = (const float*)d_in[5];
    const int*    ishp  = (const int*)d_in[6];
    float*        out   = (float*)d_out;

    const int BN = in_sizes[0] / 4;                    // B*N
    const int B  = in_sizes[1] / (256 * 256 * 256);    // from feat0
    const int N  = BN / B;

    dim3 grid(NPAIR, BN);
    roi_align_kernel<<<grid, 64, 0, stream>>>(boxes, f0, f1, f2, f3, f4, ishp, out, N);
}

// Round 4
// 248.620 us; speedup vs baseline: 1.0587x; 1.0138x over previous
//
#include <hip/hip_runtime.h>
#include <math.h>

#define CCH 256
#define CROP 7
#define NCELL 49
#define NPAIR 25   // ceil(49/2) cell pairs per box
#define WPB 4      // waves per block (occupancy: lift 1-wave workgroup cap)

// Native vector type: __builtin_nontemporal_store rejects HIP's float4 class.
typedef float f32x4 __attribute__((ext_vector_type(4)));

// Per-cell address/weight setup, suffixed so two cells can be in flight
// simultaneously (8 independent 16B global loads per wave).
#define CELL_ADDR(S, cell)                                                        \
    const int   iy##S  = (cell) / CROP;                                           \
    const int   ix##S  = (cell) % CROP;                                           \
    const float ys##S  = ry1 * Hf + (float)iy##S * ystep;                         \
    const float xs##S  = cx1 * Hf + (float)ix##S * xstep;                         \
    const float y0f##S = floorf(ys##S);                                           \
    const float x0f##S = floorf(xs##S);                                           \
    const float ly##S  = ys##S - y0f##S;                                          \
    const float lx##S  = xs##S - x0f##S;                                          \
    const int   y0##S  = (int)fminf(fmaxf(y0f##S,        0.0f), Hf);              \
    const int   y1i##S = (int)fminf(fmaxf(y0f##S + 1.0f, 0.0f), Hf);              \
    const int   x0##S  = (int)fminf(fmaxf(x0f##S,        0.0f), Hf);              \
    const int   x1i##S = (int)fminf(fmaxf(x0f##S + 1.0f, 0.0f), Hf);              \
    const bool  ok##S  = (ys##S >= 0.0f) && (ys##S <= Hf) &&                      \
                         (xs##S >= 0.0f) && (xs##S <= Hf);                        \
    const f32x4* p00##S = (const f32x4*)(f + img + ((size_t)y0##S  * s + x0##S ) * CCH) + c4; \
    const f32x4* p01##S = (const f32x4*)(f + img + ((size_t)y0##S  * s + x1i##S) * CCH) + c4; \
    const f32x4* p10##S = (const f32x4*)(f + img + ((size_t)y1i##S * s + x0##S ) * CCH) + c4; \
    const f32x4* p11##S = (const f32x4*)(f + img + ((size_t)y1i##S * s + x1i##S) * CCH) + c4;

// Bilinear lerp (identical op order to reference) + nontemporal streamed store.
#define LERP_STORE(S, v00, v01, v10, v11, cell)                                   \
    {                                                                             \
        f32x4 val;                                                                \
        float tx = v00.x + lx##S * (v01.x - v00.x);                               \
        float bx = v10.x + lx##S * (v11.x - v10.x);                               \
        val.x = tx + ly##S * (bx - tx);                                           \
        float ty = v00.y + lx##S * (v01.y - v00.y);                               \
        float by = v10.y + lx##S * (v11.y - v10.y);                               \
        val.y = ty + ly##S * (by - ty);                                           \
        float tz = v00.z + lx##S * (v01.z - v00.z);                               \
        float bz = v10.z + lx##S * (v11.z - v10.z);                               \
        val.z = tz + ly##S * (bz - tz);                                           \
        float tw = v00.w + lx##S * (v01.w - v00.w);                               \
        float bw = v10.w + lx##S * (v11.w - v10.w);                               \
        val.w = tw + ly##S * (bw - tw);                                           \
        if (!ok##S) { val.x = 0.0f; val.y = 0.0f; val.z = 0.0f; val.w = 0.0f; }   \
        __builtin_nontemporal_store(val, outbn + (size_t)(cell) * (CCH / 4));     \
    }

__global__ __launch_bounds__(64 * WPB) void roi_align_kernel(
    const f32x4* __restrict__ boxes,    // (B*N) boxes; cols [row1, col1, row2, col2]
    const float* __restrict__ f0,
    const float* __restrict__ f1,
    const float* __restrict__ f2,
    const float* __restrict__ f3,
    const float* __restrict__ f4,
    const int*  __restrict__ image_shape,
    float* __restrict__ out,
    int N)                              // boxes per batch image
{
    const int wave = threadIdx.x >> 6;            // 0..3
    const int c4   = threadIdx.x & 63;            // channels c4*4..c4*4+3
    const int pair = blockIdx.x * WPB + wave;     // 0..27; 25..27 idle
    const int bn   = blockIdx.y;                  // 0..B*N-1
    const int b    = bn / N;

    if (pair >= NPAIR) return;          // wave-uniform guard (tail waves)

    // ---- box setup (once per wave; uniform scalar work) ----
    const f32x4 box = boxes[bn];        // uniform index -> scalar load
    const float ry1 = box.x;   // row start  (col 0)
    const float cx1 = box.y;   // col start  (col 1)
    const float ry2 = box.z;   // row end    (col 2)
    const float cx2 = box.w;   // col end    (col 3)

    const float h = cx2 - cx1;
    const float w = ry2 - ry1;

    const float area  = (float)(image_shape[0] * image_shape[1]);
    const float canon = 56.0f / sqrtf(area);
    const float lvlf  = log2f(sqrtf(h * w) / canon);
    int lvl = (int)rintf(lvlf);         // half-to-even, matches jnp.round
    lvl = lvl < 0 ? 0 : (lvl > 4 ? 4 : lvl);

    const float* f; int s;
    if      (lvl == 0) { f = f0; s = 256; }
    else if (lvl == 1) { f = f1; s = 128; }
    else if (lvl == 2) { f = f2; s = 64;  }
    else if (lvl == 3) { f = f3; s = 32;  }
    else               { f = f4; s = 16;  }

    const float Hf = (float)(s - 1);    // square levels: Wf == Hf
    const float ystep = (ry2 - ry1) * Hf / 6.0f;
    const float xstep = (cx2 - cx1) * Hf / 6.0f;

    const size_t img = (size_t)b * s * s * CCH;
    f32x4* outbn = (f32x4*)(out + (size_t)bn * (NCELL * CCH)) + c4;

    const int  cA   = pair * 2;
    const bool hasB = (cA + 1) < NCELL;  // pair 24 has only cell 48
    const int  cB   = hasB ? cA + 1 : cA;   // safe duplicate load if no B

    CELL_ADDR(A, cA)
    CELL_ADDR(B, cB)

    // Issue all 8 independent 16B loads before consuming any.
    const f32x4 a00 = *p00A; const f32x4 a01 = *p01A;
    const f32x4 a10 = *p10A; const f32x4 a11 = *p11A;
    const f32x4 b00 = *p00B; const f32x4 b01 = *p01B;
    const f32x4 b10 = *p10B; const f32x4 b11 = *p11B;

    LERP_STORE(A, a00, a01, a10, a11, cA)
    if (hasB) {
        LERP_STORE(B, b00, b01, b10, b11, cB)
    }
}

extern "C" void kernel_launch(void* const* d_in, const int* in_sizes, int n_in,
                              void* d_out, int out_size, void* d_ws, size_t ws_size,
                              hipStream_t stream) {
    const f32x4*  boxes = (const f32x4*)d_in[0];
    const float*  f0    = (const float*)d_in[1];
    const float*  f1    = (const float*)d_in[2];
    const float*  f2    = (const float*)d_in[3];
    const float*  f3    = (const float*)d_in[4];
    const float*  f4    = (const float*)d_in[5];
    const int*    ishp  = (const int*)d_in[6];
    float*        out   = (float*)d_out;

    const int BN = in_sizes[0] / 4;                    // B*N
    const int B  = in_sizes[1] / (256 * 256 * 256);    // from feat0
    const int N  = BN / B;

    dim3 grid((NPAIR + WPB - 1) / WPB, BN);            // (7, B*N)
    roi_align_kernel<<<grid, 64 * WPB, 0, stream>>>(boxes, f0, f1, f2, f3, f4, ishp, out, N);
}